// Round 1
// baseline (220.278 us; speedup 1.0000x reference)
//
#include <hip/hip_runtime.h>
#include <hip/hip_bf16.h>

// Problem constants
#define N_SAMP 256
#define C_IN 2
#define T_FRAMES 120
#define V_JOINTS 13
#define LEN_KEEP 72          // int(120 * 0.6)
#define N_MASK_J 6           // int(13 * 0.5)
#define N_KEEP_J 7
#define H_DIM 64
#define E_DIM 256
#define POS_PER_SAMPLE (T_FRAMES * V_JOINTS)   // 1560

// ---------------------------------------------------------------------------
// Kernel A: per-sample index computation (frame ranks, joint masks, gathers)
// ---------------------------------------------------------------------------
__global__ void idx_kernel(const float* __restrict__ frame_noise,   // (256,120)
                           const float* __restrict__ joint_noise,   // (256,72,13)
                           int* __restrict__ ids_keep,              // (256,72) orig frame idx of kept slot
                           int* __restrict__ inv_frame,             // (256,72) t_out where frame_ids==f
                           int* __restrict__ keep_joint,            // (256,72,7) orig joint idx per slot s
                           int* __restrict__ v_out_arr)             // (256,72,7) output joint pos per slot s
{
    int n = blockIdx.x;
    int tid = threadIdx.x;

    __shared__ float noise_sh[T_FRAMES];
    __shared__ int rank_sh[T_FRAMES];
    __shared__ int frame_ids_sh[T_FRAMES];
    __shared__ int ids_keep_sh[LEN_KEEP];

    if (tid < T_FRAMES) noise_sh[tid] = frame_noise[n * T_FRAMES + tid];
    __syncthreads();

    if (tid < T_FRAMES) {
        float v = noise_sh[tid];
        int r = 0;
        for (int j = 0; j < T_FRAMES; ++j) {
            float u = noise_sh[j];
            r += (u < v || (u == v && j < tid)) ? 1 : 0;   // stable argsort rank
        }
        rank_sh[tid] = r;
    }
    __syncthreads();

    if (tid == 0) {
        int nk = 0, nm = 0;
        for (int i = 0; i < T_FRAMES; ++i) {
            if (rank_sh[i] < LEN_KEEP) {
                ids_keep_sh[nk] = i;
                frame_ids_sh[nk] = i;
                nk++;
            } else {
                frame_ids_sh[LEN_KEEP + nm] = i;
                nm++;
            }
        }
    }
    __syncthreads();

    if (tid < LEN_KEEP) ids_keep[n * LEN_KEEP + tid] = ids_keep_sh[tid];
    if (tid < T_FRAMES) {
        int val = frame_ids_sh[tid];
        if (val < LEN_KEEP) inv_frame[n * LEN_KEEP + val] = tid;
    }

    // Joint masking per kept slot f
    for (int f = tid; f < LEN_KEEP; f += blockDim.x) {
        const float* jn = joint_noise + (n * LEN_KEEP + f) * V_JOINTS;
        float jv[V_JOINTS];
        for (int v = 0; v < V_JOINTS; ++v) jv[v] = jn[v];
        int jrank[V_JOINTS];
        for (int v = 0; v < V_JOINTS; ++v) {
            int r = 0;
            for (int u = 0; u < V_JOINTS; ++u)
                r += (jv[u] < jv[v] || (jv[u] == jv[v] && u < v)) ? 1 : 0;
            jrank[v] = r;
        }
        // masked = 6 smallest-noise joints (rank < 6)
        int comb[V_JOINTS];
        int idx = 0;
        for (int v = 0; v < V_JOINTS; ++v) if (jrank[v] >= N_MASK_J) comb[idx++] = v; // unmasked, ascending
        for (int v = 0; v < V_JOINTS; ++v) if (jrank[v] <  N_MASK_J) comb[idx++] = v; // masked, ascending
        for (int s = 0; s < N_KEEP_J; ++s)
            keep_joint[(n * LEN_KEEP + f) * N_KEEP_J + s] = comb[s];
        for (int v = 0; v < V_JOINTS; ++v) {
            int s = comb[v];
            if (s < N_KEEP_J) v_out_arr[(n * LEN_KEEP + f) * N_KEEP_J + s] = v;
        }
    }
}

// ---------------------------------------------------------------------------
// Kernel B: dpeproj[o,t,v] = sum_c w_dec[o,c] * dec_pos_embed[c,t,v]
// ---------------------------------------------------------------------------
__global__ void dpe_kernel(const float* __restrict__ w_dec,          // (2,256)
                           const float* __restrict__ dec_pos_embed,  // (1,256,120,13)
                           float* __restrict__ dpeproj)              // (2,1560)
{
    int i = blockIdx.x * blockDim.x + threadIdx.x;
    if (i >= C_IN * POS_PER_SAMPLE) return;
    int o = i / POS_PER_SAMPLE;
    int p = i % POS_PER_SAMPLE;
    float s = 0.f;
    for (int c = 0; c < E_DIM; ++c)
        s += w_dec[o * E_DIM + c] * dec_pos_embed[c * POS_PER_SAMPLE + p];
    dpeproj[i] = s;
}

// ---------------------------------------------------------------------------
// Kernel C: out[n, :, :, :] = dpeproj  (default for all un-sourced positions)
// ---------------------------------------------------------------------------
__global__ void init_kernel(const float* __restrict__ dpeproj,
                            float* __restrict__ out)
{
    int n = blockIdx.y;
    int i = blockIdx.x * blockDim.x + threadIdx.x;
    if (i < C_IN * POS_PER_SAMPLE)
        out[n * C_IN * POS_PER_SAMPLE + i] = dpeproj[i];
}

// ---------------------------------------------------------------------------
// Kernel D: per (n, kept-frame-slot f): encoder MLP + scatter to output
// ---------------------------------------------------------------------------
__global__ __launch_bounds__(256)
void enc_kernel(const float* __restrict__ x,          // (256,2,120,13,1)
                const float* __restrict__ pos_embed,  // (1,2,120,13)
                const float* __restrict__ w_in,       // (64,2)
                const float* __restrict__ b_in,       // (64,)
                const float* __restrict__ w_enc,      // (256,64)
                const float* __restrict__ w_dec,      // (2,256)
                const float* __restrict__ dpeproj,    // (2,1560)
                const int* __restrict__ ids_keep,
                const int* __restrict__ inv_frame,
                const int* __restrict__ keep_joint,
                const int* __restrict__ v_out_arr,
                float* __restrict__ out)              // (256,2,120,13,1)
{
    int nf = blockIdx.x;                 // n*72 + f
    int n = nf / LEN_KEEP;
    int tid = threadIdx.x;               // 256 threads

    __shared__ float xm_sh[C_IN][N_KEEP_J];
    __shared__ float h_sh[N_KEEP_J][H_DIM];
    __shared__ float e_sh[N_KEEP_J][E_DIM + 1];
    __shared__ int jk_sh[N_KEEP_J], vo_sh[N_KEEP_J];
    __shared__ int tsrc_sh, tout_sh;

    if (tid == 0) { tsrc_sh = ids_keep[nf]; tout_sh = inv_frame[nf]; }
    if (tid < N_KEEP_J) {
        jk_sh[tid] = keep_joint[nf * N_KEEP_J + tid];
        vo_sh[tid] = v_out_arr[nf * N_KEEP_J + tid];
    }
    __syncthreads();

    if (tid < C_IN * N_KEEP_J) {
        int c = tid / N_KEEP_J, s = tid % N_KEEP_J;
        int t = tsrc_sh, j = jk_sh[s];
        xm_sh[c][s] = x[((n * C_IN + c) * T_FRAMES + t) * V_JOINTS + j]
                    + pos_embed[(c * T_FRAMES + t) * V_JOINTS + j];
    }
    __syncthreads();

    // h[s][k] = leaky(w_in[k,0]*x0 + w_in[k,1]*x1 + b[k]) : 448 outputs
    for (int i = tid; i < N_KEEP_J * H_DIM; i += 256) {
        int s = i >> 6, k = i & 63;
        float hv = w_in[k * 2 + 0] * xm_sh[0][s] + w_in[k * 2 + 1] * xm_sh[1][s] + b_in[k];
        h_sh[s][k] = hv >= 0.f ? hv : 0.1f * hv;
    }
    __syncthreads();

    // e[s][c] = leaky(sum_k w_enc[c,k] * h[s][k]) ; thread tid owns channel c=tid
    {
        float wr[H_DIM];
        #pragma unroll
        for (int k = 0; k < H_DIM; ++k) wr[k] = w_enc[tid * H_DIM + k];
        for (int s = 0; s < N_KEEP_J; ++s) {
            float acc = 0.f;
            #pragma unroll
            for (int k = 0; k < H_DIM; ++k) acc += wr[k] * h_sh[s][k];
            acc = acc >= 0.f ? acc : 0.1f * acc;
            e_sh[s][tid] = acc;
        }
    }
    __syncthreads();

    // project to 2 channels and scatter-store: 14 dots of length 256
    if (tid < C_IN * N_KEEP_J) {
        int s = tid >> 1, o = tid & 1;
        float acc = 0.f;
        for (int c = 0; c < E_DIM; ++c) acc += w_dec[o * E_DIM + c] * e_sh[s][c];
        int t = tout_sh, v = vo_sh[s];
        out[((n * C_IN + o) * T_FRAMES + t) * V_JOINTS + v]
            = acc + dpeproj[(o * T_FRAMES + t) * V_JOINTS + v];
    }
}

// ---------------------------------------------------------------------------
extern "C" void kernel_launch(void* const* d_in, const int* in_sizes, int n_in,
                              void* d_out, int out_size, void* d_ws, size_t ws_size,
                              hipStream_t stream) {
    const float* x             = (const float*)d_in[0];
    const float* frame_noise   = (const float*)d_in[1];
    const float* joint_noise   = (const float*)d_in[2];
    const float* pos_embed     = (const float*)d_in[3];
    const float* dec_pos_embed = (const float*)d_in[4];
    const float* w_in          = (const float*)d_in[5];
    const float* b_in          = (const float*)d_in[6];
    const float* w_enc         = (const float*)d_in[7];
    const float* w_dec         = (const float*)d_in[8];
    float* out = (float*)d_out;

    // ws layout (all 4-byte elements)
    int* ids_keep   = (int*)d_ws;                          // 256*72
    int* inv_frame  = ids_keep   + N_SAMP * LEN_KEEP;      // 256*72
    int* keep_joint = inv_frame  + N_SAMP * LEN_KEEP;      // 256*72*7
    int* v_out_arr  = keep_joint + N_SAMP * LEN_KEEP * N_KEEP_J;
    float* dpeproj  = (float*)(v_out_arr + N_SAMP * LEN_KEEP * N_KEEP_J); // 2*1560

    idx_kernel<<<N_SAMP, 128, 0, stream>>>(frame_noise, joint_noise,
                                           ids_keep, inv_frame, keep_joint, v_out_arr);

    dpe_kernel<<<(C_IN * POS_PER_SAMPLE + 255) / 256, 256, 0, stream>>>(
        w_dec, dec_pos_embed, dpeproj);

    dim3 ginit((C_IN * POS_PER_SAMPLE + 255) / 256, N_SAMP);
    init_kernel<<<ginit, 256, 0, stream>>>(dpeproj, out);

    enc_kernel<<<N_SAMP * LEN_KEEP, 256, 0, stream>>>(
        x, pos_embed, w_in, b_in, w_enc, w_dec, dpeproj,
        ids_keep, inv_frame, keep_joint, v_out_arr, out);
}

// Round 3
// 66.735 us; speedup vs baseline: 3.3008x; 3.3008x over previous
//
#include <hip/hip_runtime.h>
#include <hip/hip_bf16.h>

// Problem constants
#define N_SAMP 256
#define C_IN 2
#define T_FRAMES 120
#define V_JOINTS 13
#define LEN_KEEP 72          // int(120 * 0.6)
#define N_MASK_J 6           // int(13 * 0.5)
#define N_KEEP_J 7
#define H_DIM 64
#define E_DIM 256
#define POS_PER_SAMPLE (T_FRAMES * V_JOINTS)   // 1560

typedef __attribute__((ext_vector_type(8))) __bf16 bf16x8;
typedef __attribute__((ext_vector_type(4))) float f32x4;

// ---------------------------------------------------------------------------
// Kernel 1 (prep): role-split blocks
//   blocks [0,256)    : per-sample index computation (frame ranks, joint masks)
//   blocks [256,269)  : dpeproj = w_dec . dec_pos_embed
//   blocks [269,333)  : w_enc fp32 -> bf16
// ---------------------------------------------------------------------------
__global__ __launch_bounds__(256)
void prep_kernel(const float* __restrict__ frame_noise,   // (256,120)
                 const float* __restrict__ joint_noise,   // (256,72,13)
                 const float* __restrict__ w_dec,         // (2,256)
                 const float* __restrict__ dec_pos_embed, // (1,256,120,13)
                 const float* __restrict__ w_enc,         // (256,64)
                 int* __restrict__ ids_keep,              // (256,72)
                 int* __restrict__ inv_frame,             // (256,72)
                 int* __restrict__ keep_joint,            // (256,72,7)
                 int* __restrict__ v_out_arr,             // (256,72,7)
                 float* __restrict__ dpeproj,             // (2,1560)
                 __bf16* __restrict__ wbf)                // (256,64)
{
    int bid = blockIdx.x;
    int tid = threadIdx.x;

    if (bid >= 256) {
        if (bid < 269) {
            int i = (bid - 256) * 256 + tid;
            if (i < C_IN * POS_PER_SAMPLE) {
                int o = i / POS_PER_SAMPLE;
                int p = i - o * POS_PER_SAMPLE;
                float s = 0.f;
                for (int c = 0; c < E_DIM; ++c)
                    s += w_dec[o * E_DIM + c] * dec_pos_embed[c * POS_PER_SAMPLE + p];
                dpeproj[i] = s;
            }
        } else {
            int i = (bid - 269) * 256 + tid;
            if (i < E_DIM * H_DIM) wbf[i] = (__bf16)w_enc[i];
        }
        return;
    }

    int n = bid;
    __shared__ float noise_sh[T_FRAMES];
    __shared__ int rank_sh[T_FRAMES];
    __shared__ int frame_ids_sh[T_FRAMES];
    __shared__ int ids_keep_sh[LEN_KEEP];

    if (tid < T_FRAMES) noise_sh[tid] = frame_noise[n * T_FRAMES + tid];
    __syncthreads();

    if (tid < T_FRAMES) {
        float v = noise_sh[tid];
        int r = 0;
        for (int j = 0; j < T_FRAMES; ++j) {
            float u = noise_sh[j];
            r += (u < v || (u == v && j < tid)) ? 1 : 0;   // stable argsort rank
        }
        rank_sh[tid] = r;
    }
    __syncthreads();

    if (tid == 0) {
        int nk = 0, nm = 0;
        for (int i = 0; i < T_FRAMES; ++i) {
            if (rank_sh[i] < LEN_KEEP) {
                ids_keep_sh[nk] = i;
                frame_ids_sh[nk] = i;
                nk++;
            } else {
                frame_ids_sh[LEN_KEEP + nm] = i;
                nm++;
            }
        }
    }
    __syncthreads();

    if (tid < LEN_KEEP) ids_keep[n * LEN_KEEP + tid] = ids_keep_sh[tid];
    if (tid < T_FRAMES) {
        int val = frame_ids_sh[tid];
        if (val < LEN_KEEP) inv_frame[n * LEN_KEEP + val] = tid;
    }

    for (int f = tid; f < LEN_KEEP; f += blockDim.x) {
        const float* jn = joint_noise + (n * LEN_KEEP + f) * V_JOINTS;
        float jv[V_JOINTS];
        for (int v = 0; v < V_JOINTS; ++v) jv[v] = jn[v];
        int jrank[V_JOINTS];
        for (int v = 0; v < V_JOINTS; ++v) {
            int r = 0;
            for (int u = 0; u < V_JOINTS; ++u)
                r += (jv[u] < jv[v] || (jv[u] == jv[v] && u < v)) ? 1 : 0;
            jrank[v] = r;
        }
        int comb[V_JOINTS];
        int idx = 0;
        for (int v = 0; v < V_JOINTS; ++v) if (jrank[v] >= N_MASK_J) comb[idx++] = v;
        for (int v = 0; v < V_JOINTS; ++v) if (jrank[v] <  N_MASK_J) comb[idx++] = v;
        for (int s = 0; s < N_KEEP_J; ++s)
            keep_joint[(n * LEN_KEEP + f) * N_KEEP_J + s] = comb[s];
        for (int v = 0; v < V_JOINTS; ++v) {
            int s = comb[v];
            if (s < N_KEEP_J) v_out_arr[(n * LEN_KEEP + f) * N_KEEP_J + s] = v;
        }
    }
}

// ---------------------------------------------------------------------------
// Kernel 2: out[n, :, :, :] = dpeproj  (default for all un-sourced positions)
// ---------------------------------------------------------------------------
__global__ void init_kernel(const float* __restrict__ dpeproj,
                            float* __restrict__ out)
{
    int n = blockIdx.y;
    int i = blockIdx.x * blockDim.x + threadIdx.x;
    if (i < C_IN * POS_PER_SAMPLE)
        out[n * C_IN * POS_PER_SAMPLE + i] = dpeproj[i];
}

// ---------------------------------------------------------------------------
// Kernel 3: MFMA encoder + fused decoder, quarter-sample blocks
// ---------------------------------------------------------------------------
#define FQ 18                       // frames per block (72/4)
#define NPOS (FQ * N_KEEP_J)        // 126 positions
#define NROW 128                    // padded rows
#define NPT 8                       // 128/16 position tiles

__global__ __launch_bounds__(256)
void enc_mfma_kernel(const float* __restrict__ x,          // (256,2,120,13)
                     const float* __restrict__ pos_embed,  // (1,2,120,13)
                     const float* __restrict__ w_in,       // (64,2)
                     const float* __restrict__ b_in,       // (64,)
                     const __bf16* __restrict__ wbf,       // (256,64) bf16
                     const float* __restrict__ w_dec,      // (2,256)
                     const float* __restrict__ dpeproj,    // (2,1560)
                     const int* __restrict__ ids_keep,
                     const int* __restrict__ inv_frame,
                     const int* __restrict__ keep_joint,
                     const int* __restrict__ v_out_arr,
                     float* __restrict__ out)
{
    // h in bf16, [128 rows][64 k], row stride 128B, XOR-swizzled (G4)
    __shared__ __align__(16) char h_raw[NROW * 128];
    __shared__ float2 xm_sh[NROW];
    __shared__ int dst_sh[NROW];

    int bid = blockIdx.x;
    int n = bid >> 2;
    int fbase = (bid & 3) * FQ;
    int tid = threadIdx.x;

    // ---- phase 0: gather metadata + x (one position per thread) ----
    if (tid < NROW) {
        if (tid < NPOS) {
            int fl = tid / N_KEEP_J;
            int s = tid - fl * N_KEEP_J;
            int nf = n * LEN_KEEP + fbase + fl;
            int tsrc = ids_keep[nf];
            int tout = inv_frame[nf];
            int j = keep_joint[nf * N_KEEP_J + s];
            int v = v_out_arr[nf * N_KEEP_J + s];
            int so = tsrc * V_JOINTS + j;
            float x0 = x[(n * 2 + 0) * POS_PER_SAMPLE + so] + pos_embed[so];
            float x1 = x[(n * 2 + 1) * POS_PER_SAMPLE + so] + pos_embed[POS_PER_SAMPLE + so];
            xm_sh[tid] = make_float2(x0, x1);
            dst_sh[tid] = tout * V_JOINTS + v;
        } else {
            xm_sh[tid] = make_float2(0.f, 0.f);
            dst_sh[tid] = 0;
        }
    }
    __syncthreads();

    // ---- phase 1: h[p][k] = leaky(w_in[k,:].xm[p] + b[k]) -> bf16 LDS ----
    {
        int kq = tid & 63;
        int pg = tid >> 6;
        float wi0 = w_in[kq * 2 + 0], wi1 = w_in[kq * 2 + 1], bk = b_in[kq];
        for (int p = pg; p < NROW; p += 4) {
            float2 xm = xm_sh[p];
            float hv = fmaf(wi0, xm.x, fmaf(wi1, xm.y, bk));
            hv = fmaxf(hv, 0.1f * hv);                    // leaky
            int off = (p * 128 + kq * 2) ^ ((p & 7) << 4);
            *(__bf16*)(h_raw + off) = (__bf16)hv;
        }
    }
    __syncthreads();

    // ---- phase 2: per wave, 2 position-tiles; MFMA e-stage + fused decoder ----
    int lane = tid & 63;
    int wave = tid >> 6;
    int g = lane >> 4;       // k-group / D-row-group
    int r16 = lane & 15;     // A-row (channel) / B-col (position)

    // Preload all w_enc A-fragments: wfr[ct][ks] = w[ct*16+r16][ks*32+g*8 .. +8]
    bf16x8 wfr[16][2];
    const bf16x8* wq = (const bf16x8*)wbf;
    #pragma unroll
    for (int ct = 0; ct < 16; ++ct) {
        wfr[ct][0] = wq[(ct * 16 + r16) * 8 + 0 + g];
        wfr[ct][1] = wq[(ct * 16 + r16) * 8 + 4 + g];
    }

    for (int pt = wave; pt < NPT; pt += 4) {
        int row = pt * 16 + r16;
        int swz = (row & 7) << 4;
        // B-fragments: h[row][ks*32 + g*8 .. +8]  (same k-map as A -> cancels)
        bf16x8 b0 = *(const bf16x8*)(h_raw + ((row * 128 + g * 16) ^ swz));
        bf16x8 b1 = *(const bf16x8*)(h_raw + ((row * 128 + 64 + g * 16) ^ swz));

        float pd0 = 0.f, pd1 = 0.f;
        #pragma unroll
        for (int ct = 0; ct < 16; ++ct) {
            f32x4 acc = {0.f, 0.f, 0.f, 0.f};
            acc = __builtin_amdgcn_mfma_f32_16x16x32_bf16(wfr[ct][0], b0, acc, 0, 0, 0);
            acc = __builtin_amdgcn_mfma_f32_16x16x32_bf16(wfr[ct][1], b1, acc, 0, 0, 0);
            // D layout: channel c = ct*16 + g*4 + r, position p = pt*16 + r16
            f32x4 wd0 = *(const f32x4*)(w_dec + ct * 16 + g * 4);
            f32x4 wd1 = *(const f32x4*)(w_dec + E_DIM + ct * 16 + g * 4);
            #pragma unroll
            for (int r = 0; r < 4; ++r) {
                float e = acc[r];
                e = fmaxf(e, 0.1f * e);                   // leaky
                pd0 = fmaf(wd0[r], e, pd0);
                pd1 = fmaf(wd1[r], e, pd1);
            }
        }
        // reduce decoder partials over the 4 g-groups
        pd0 += __shfl_xor(pd0, 16); pd0 += __shfl_xor(pd0, 32);
        pd1 += __shfl_xor(pd1, 16); pd1 += __shfl_xor(pd1, 32);

        int p = pt * 16 + r16;
        if (lane < 16 && p < NPOS) {
            int off = dst_sh[p];
            out[(n * 2 + 0) * POS_PER_SAMPLE + off] = pd0 + dpeproj[off];
            out[(n * 2 + 1) * POS_PER_SAMPLE + off] = pd1 + dpeproj[POS_PER_SAMPLE + off];
        }
    }
}

// ---------------------------------------------------------------------------
extern "C" void kernel_launch(void* const* d_in, const int* in_sizes, int n_in,
                              void* d_out, int out_size, void* d_ws, size_t ws_size,
                              hipStream_t stream) {
    const float* x             = (const float*)d_in[0];
    const float* frame_noise   = (const float*)d_in[1];
    const float* joint_noise   = (const float*)d_in[2];
    const float* pos_embed     = (const float*)d_in[3];
    const float* dec_pos_embed = (const float*)d_in[4];
    const float* w_in          = (const float*)d_in[5];
    const float* b_in          = (const float*)d_in[6];
    const float* w_enc         = (const float*)d_in[7];
    const float* w_dec         = (const float*)d_in[8];
    float* out = (float*)d_out;

    // ws layout (4-byte elements, wbf 16B-aligned at the end)
    int* ids_keep   = (int*)d_ws;                                   // 256*72
    int* inv_frame  = ids_keep   + N_SAMP * LEN_KEEP;               // 256*72
    int* keep_joint = inv_frame  + N_SAMP * LEN_KEEP;               // 256*72*7
    int* v_out_arr  = keep_joint + N_SAMP * LEN_KEEP * N_KEEP_J;    // 256*72*7
    float* dpeproj  = (float*)(v_out_arr + N_SAMP * LEN_KEEP * N_KEEP_J); // 2*1560
    __bf16* wbf     = (__bf16*)(dpeproj + C_IN * POS_PER_SAMPLE);   // 256*64 bf16

    prep_kernel<<<333, 256, 0, stream>>>(frame_noise, joint_noise, w_dec,
                                         dec_pos_embed, w_enc,
                                         ids_keep, inv_frame, keep_joint, v_out_arr,
                                         dpeproj, wbf);

    dim3 ginit((C_IN * POS_PER_SAMPLE + 255) / 256, N_SAMP);
    init_kernel<<<ginit, 256, 0, stream>>>(dpeproj, out);

    enc_mfma_kernel<<<N_SAMP * 4, 256, 0, stream>>>(
        x, pos_embed, w_in, b_in, wbf, w_dec, dpeproj,
        ids_keep, inv_frame, keep_joint, v_out_arr, out);
}

// Round 5
// 56.322 us; speedup vs baseline: 3.9110x; 1.1849x over previous
//
#include <hip/hip_runtime.h>
#include <hip/hip_bf16.h>

// Problem constants
#define N_SAMP 256
#define C_IN 2
#define T_FRAMES 120
#define V_JOINTS 13
#define LEN_KEEP 72          // int(120 * 0.6)
#define N_MASK_J 6           // int(13 * 0.5)
#define N_KEEP_J 7
#define H_DIM 64
#define E_DIM 256
#define POS_PER_SAMPLE (T_FRAMES * V_JOINTS)   // 1560
#define NPOS (LEN_KEEP * N_KEEP_J)             // 504 real positions
#define NROW 512                               // padded rows (16-multiple)
#define NPT (NROW / 16)                        // 32 position tiles
#define THREADS 512

typedef __attribute__((ext_vector_type(8))) __bf16 bf16x8;
typedef __attribute__((ext_vector_type(4))) float f32x4;

// ---------------------------------------------------------------------------
// Kernel 1 (prep): blocks [0,13): dpeproj = w_dec . dec_pos_embed
//                  blocks [13,77): w_enc fp32 -> bf16
// ---------------------------------------------------------------------------
__global__ __launch_bounds__(256)
void prep_kernel(const float* __restrict__ w_dec,         // (2,256)
                 const float* __restrict__ dec_pos_embed, // (1,256,120,13)
                 const float* __restrict__ w_enc,         // (256,64)
                 float* __restrict__ dpeproj,             // (2,1560)
                 __bf16* __restrict__ wbf)                // (256,64)
{
    int bid = blockIdx.x;
    int tid = threadIdx.x;
    if (bid < 13) {
        int i = bid * 256 + tid;
        if (i < C_IN * POS_PER_SAMPLE) {
            int o = i / POS_PER_SAMPLE;
            int p = i - o * POS_PER_SAMPLE;
            float s = 0.f;
            for (int c = 0; c < E_DIM; ++c)
                s += w_dec[o * E_DIM + c] * dec_pos_embed[c * POS_PER_SAMPLE + p];
            dpeproj[i] = s;
        }
    } else {
        int i = (bid - 13) * 256 + tid;
        if (i < E_DIM * H_DIM) wbf[i] = (__bf16)w_enc[i];
    }
}

// ---------------------------------------------------------------------------
// Kernel 2: fully fused per-sample kernel. 256 blocks x 512 threads.
//   phase A: per-sample masking indices (all-parallel, no serial section)
//   phase B: gather x + pos_embed for 504 kept positions
//   phase C: h = leaky(W_in x + b) -> bf16 LDS [512][64], XOR-swizzled
//   phase D: MFMA 64->256 e-stage + fused 256->2 decoder -> pdbuf (LDS)
//   phase E: out[n] = dpeproj + scatter(pdbuf) via LDS reverse map
// ---------------------------------------------------------------------------
__global__ __launch_bounds__(THREADS)
void fused_kernel(const float* __restrict__ x,            // (256,2,120,13)
                  const float* __restrict__ pos_embed,    // (1,2,120,13)
                  const float* __restrict__ w_in,         // (64,2)
                  const float* __restrict__ b_in,         // (64,)
                  const __bf16* __restrict__ wbf,         // (256,64) bf16
                  const float* __restrict__ w_dec,        // (2,256)
                  const float* __restrict__ dpeproj,      // (2,1560)
                  const float* __restrict__ frame_noise,  // (256,120)
                  const float* __restrict__ joint_noise,  // (256,72,13)
                  float* __restrict__ out)                // (256,2,120,13)
{
    __shared__ __align__(16) char h_raw[NROW * 128];   // 64 KB bf16 [512][64]
    __shared__ float2 xm_sh[NROW];
    __shared__ int src_sh[NPOS];
    __shared__ short rev_sh[POS_PER_SAMPLE];           // -1 or position index
    __shared__ float pdbuf[NPOS][2];
    __shared__ float noise_sh[T_FRAMES];
    __shared__ int rank_sh[T_FRAMES];
    __shared__ int ids_keep_sh[LEN_KEEP];
    __shared__ int tout_sh[LEN_KEEP];

    int n = blockIdx.x;
    int tid = threadIdx.x;
    int lane = tid & 63, wave = tid >> 6;
    int g = lane >> 4;       // k-group / D-row-group
    int r16 = lane & 15;     // A-row (channel) / B-col (position)

    // ---- hoisted w_enc A-fragment loads (latency hides under phases A-C) ----
    bf16x8 wfr[16][2];
    {
        const bf16x8* wq = (const bf16x8*)wbf;
        #pragma unroll
        for (int ct = 0; ct < 16; ++ct) {
            wfr[ct][0] = wq[(ct * 16 + r16) * 8 + 0 + g];
            wfr[ct][1] = wq[(ct * 16 + r16) * 8 + 4 + g];
        }
    }

    // ---- phase A: indices ----
    if (tid < T_FRAMES) noise_sh[tid] = frame_noise[n * T_FRAMES + tid];
    for (int i = tid; i < POS_PER_SAMPLE; i += THREADS) rev_sh[i] = -1;
    __syncthreads();

    if (tid < T_FRAMES) {
        float v = noise_sh[tid];
        int r = 0;
        for (int j = 0; j < T_FRAMES; ++j) {
            float u = noise_sh[j];
            r += (u < v || (u == v && j < tid)) ? 1 : 0;   // stable argsort rank
        }
        rank_sh[tid] = r;
    }
    __syncthreads();

    if (tid < T_FRAMES) {
        int kc = 0;                                  // #kept frames with index < tid
        for (int j = 0; j < tid; ++j) kc += (rank_sh[j] < LEN_KEEP) ? 1 : 0;
        if (rank_sh[tid] < LEN_KEEP) ids_keep_sh[kc] = tid;
        // tout_sh[v]: output frame t where frame_ids[t] == v (v < 72)
        if (tid < LEN_KEEP)
            tout_sh[tid] = (rank_sh[tid] < LEN_KEEP) ? kc : LEN_KEEP + (tid - kc);
    }
    __syncthreads();

    if (tid < LEN_KEEP) {
        int f = tid;
        const float* jn = joint_noise + (n * LEN_KEEP + f) * V_JOINTS;
        float jv[V_JOINTS];
        for (int v = 0; v < V_JOINTS; ++v) jv[v] = jn[v];
        int jrank[V_JOINTS];
        for (int v = 0; v < V_JOINTS; ++v) {
            int r = 0;
            for (int u = 0; u < V_JOINTS; ++u)
                r += (jv[u] < jv[v] || (jv[u] == jv[v] && u < v)) ? 1 : 0;
            jrank[v] = r;
        }
        int comb[V_JOINTS];
        int idx = 0;
        for (int v = 0; v < V_JOINTS; ++v) if (jrank[v] >= N_MASK_J) comb[idx++] = v;
        for (int v = 0; v < V_JOINTS; ++v) if (jrank[v] <  N_MASK_J) comb[idx++] = v;
        int vout[N_KEEP_J];
        for (int v = 0; v < V_JOINTS; ++v) {
            int s = comb[v];
            if (s < N_KEEP_J) vout[s] = v;
        }
        int tsrc = ids_keep_sh[f];
        int tout = tout_sh[f];
        for (int s = 0; s < N_KEEP_J; ++s) {
            int p = f * N_KEEP_J + s;
            src_sh[p] = tsrc * V_JOINTS + comb[s];
            int d = tout * V_JOINTS + vout[s];
            rev_sh[d] = (short)p;
        }
    }
    __syncthreads();

    // ---- phase B: gather x + pos_embed ----
    if (tid < NROW) {
        if (tid < NPOS) {
            int so = src_sh[tid];
            float x0 = x[(n * 2 + 0) * POS_PER_SAMPLE + so] + pos_embed[so];
            float x1 = x[(n * 2 + 1) * POS_PER_SAMPLE + so] + pos_embed[POS_PER_SAMPLE + so];
            xm_sh[tid] = make_float2(x0, x1);
        } else {
            xm_sh[tid] = make_float2(0.f, 0.f);
        }
    }
    __syncthreads();

    // ---- phase C: h[p][k] = leaky(w_in[k,:].xm[p] + b[k]) -> bf16 LDS ----
    {
        int kq = lane;
        float wi0 = w_in[kq * 2 + 0], wi1 = w_in[kq * 2 + 1], bk = b_in[kq];
        for (int p = wave; p < NROW; p += 8) {
            float2 xm = xm_sh[p];
            float hv = fmaf(wi0, xm.x, fmaf(wi1, xm.y, bk));
            hv = fmaxf(hv, 0.1f * hv);                    // leaky
            int off = (p * 128 + kq * 2) ^ ((p & 7) << 4);
            *(__bf16*)(h_raw + off) = (__bf16)hv;
        }
    }
    __syncthreads();

    // ---- phase D: MFMA e-stage + fused decoder, 4 tiles per wave ----
    for (int pt = wave; pt < NPT; pt += 8) {
        int row = pt * 16 + r16;
        int swz = (row & 7) << 4;
        bf16x8 b0 = *(const bf16x8*)(h_raw + ((row * 128 + g * 16) ^ swz));
        bf16x8 b1 = *(const bf16x8*)(h_raw + ((row * 128 + 64 + g * 16) ^ swz));

        float pd0 = 0.f, pd1 = 0.f;
        #pragma unroll
        for (int ct = 0; ct < 16; ++ct) {
            f32x4 acc = {0.f, 0.f, 0.f, 0.f};
            acc = __builtin_amdgcn_mfma_f32_16x16x32_bf16(wfr[ct][0], b0, acc, 0, 0, 0);
            acc = __builtin_amdgcn_mfma_f32_16x16x32_bf16(wfr[ct][1], b1, acc, 0, 0, 0);
            // D layout: channel c = ct*16 + g*4 + r, position p = pt*16 + r16
            f32x4 wd0 = *(const f32x4*)(w_dec + ct * 16 + g * 4);
            f32x4 wd1 = *(const f32x4*)(w_dec + E_DIM + ct * 16 + g * 4);
            #pragma unroll
            for (int r = 0; r < 4; ++r) {
                float e = acc[r];
                e = fmaxf(e, 0.1f * e);                   // leaky
                pd0 = fmaf(wd0[r], e, pd0);
                pd1 = fmaf(wd1[r], e, pd1);
            }
        }
        pd0 += __shfl_xor(pd0, 16); pd0 += __shfl_xor(pd0, 32);
        pd1 += __shfl_xor(pd1, 16); pd1 += __shfl_xor(pd1, 32);

        int p = pt * 16 + r16;
        if (lane < 16 && p < NPOS) {
            pdbuf[p][0] = pd0;
            pdbuf[p][1] = pd1;
        }
    }
    __syncthreads();

    // ---- phase E: final write: out = dpeproj + scattered decoder result ----
    {
        float* outn = out + n * C_IN * POS_PER_SAMPLE;
        for (int i = tid; i < C_IN * POS_PER_SAMPLE; i += THREADS) {
            int o = (i >= POS_PER_SAMPLE) ? 1 : 0;
            int pos = i - o * POS_PER_SAMPLE;
            float v = dpeproj[i];
            int p = rev_sh[pos];
            if (p >= 0) v += pdbuf[p][o];
            outn[i] = v;
        }
    }
}

// ---------------------------------------------------------------------------
extern "C" void kernel_launch(void* const* d_in, const int* in_sizes, int n_in,
                              void* d_out, int out_size, void* d_ws, size_t ws_size,
                              hipStream_t stream) {
    const float* x             = (const float*)d_in[0];
    const float* frame_noise   = (const float*)d_in[1];
    const float* joint_noise   = (const float*)d_in[2];
    const float* pos_embed     = (const float*)d_in[3];
    const float* dec_pos_embed = (const float*)d_in[4];
    const float* w_in          = (const float*)d_in[5];
    const float* b_in          = (const float*)d_in[6];
    const float* w_enc         = (const float*)d_in[7];
    const float* w_dec         = (const float*)d_in[8];
    float* out = (float*)d_out;

    // ws layout: dpeproj (3120 f32, 12480 B, 16B-aligned) then wbf (16384 bf16)
    float* dpeproj = (float*)d_ws;
    __bf16* wbf    = (__bf16*)(dpeproj + C_IN * POS_PER_SAMPLE);

    prep_kernel<<<77, 256, 0, stream>>>(w_dec, dec_pos_embed, w_enc, dpeproj, wbf);

    fused_kernel<<<N_SAMP, THREADS, 0, stream>>>(
        x, pos_embed, w_in, b_in, wbf, w_dec, dpeproj,
        frame_noise, joint_noise, out);
}

// Round 6
// 37.009 us; speedup vs baseline: 5.9521x; 1.5219x over previous
//
#include <hip/hip_runtime.h>
#include <hip/hip_bf16.h>

// Problem constants
#define N_SAMP 256
#define C_IN 2
#define T_FRAMES 120
#define V_JOINTS 13
#define LEN_KEEP 72          // int(120 * 0.6)
#define N_MASK_J 6           // int(13 * 0.5)
#define N_KEEP_J 7
#define H_DIM 64
#define E_DIM 256
#define POS_PER_SAMPLE (T_FRAMES * V_JOINTS)   // 1560
#define NPOS (LEN_KEEP * N_KEEP_J)             // 504 real positions
#define NROW 512                               // padded rows (16-multiple)
#define NPT (NROW / 16)                        // 32 position tiles
#define THREADS 512

typedef __attribute__((ext_vector_type(8))) __bf16 bf16x8;
typedef __attribute__((ext_vector_type(4))) float f32x4;

// ---------------------------------------------------------------------------
// Kernel 1 (prep): blocks [0,13): dpeproj = w_dec . dec_pos_embed
//                  blocks [13,77): w_enc fp32 -> bf16
// ---------------------------------------------------------------------------
__global__ __launch_bounds__(256)
void prep_kernel(const float* __restrict__ w_dec,         // (2,256)
                 const float* __restrict__ dec_pos_embed, // (1,256,120,13)
                 const float* __restrict__ w_enc,         // (256,64)
                 float* __restrict__ dpeproj,             // (2,1560)
                 __bf16* __restrict__ wbf)                // (256,64)
{
    int bid = blockIdx.x;
    int tid = threadIdx.x;
    if (bid < 13) {
        int i = bid * 256 + tid;
        if (i < C_IN * POS_PER_SAMPLE) {
            int o = i / POS_PER_SAMPLE;
            int p = i - o * POS_PER_SAMPLE;
            float s = 0.f;
            for (int c = 0; c < E_DIM; ++c)
                s += w_dec[o * E_DIM + c] * dec_pos_embed[c * POS_PER_SAMPLE + p];
            dpeproj[i] = s;
        }
    } else {
        int i = (bid - 13) * 256 + tid;
        if (i < E_DIM * H_DIM) wbf[i] = (__bf16)w_enc[i];
    }
}

// ---------------------------------------------------------------------------
// Kernel 2: fully fused per-sample kernel. 256 blocks x 512 threads.
//   phase A: per-sample masking indices (all-parallel)
//   phase B: gather x + pos_embed for 504 kept positions
//   phase C: h = leaky(W_in x + b) -> bf16 LDS [512][64], XOR-swizzled
//   phase D: MFMA 64->256 e-stage + fused 256->2 decoder, waves split as
//            (ctg: 4 channel-tiles) x (ptg: 16 position-tiles); partial
//            decoder sums -> pdpart[4][NPOS][2] (LDS)
//   phase E: out[n] = dpeproj + sum_ctg pdpart via LDS reverse map
// ---------------------------------------------------------------------------
__global__ __launch_bounds__(THREADS, 1)
void fused_kernel(const float* __restrict__ x,            // (256,2,120,13)
                  const float* __restrict__ pos_embed,    // (1,2,120,13)
                  const float* __restrict__ w_in,         // (64,2)
                  const float* __restrict__ b_in,         // (64,)
                  const __bf16* __restrict__ wbf,         // (256,64) bf16
                  const float* __restrict__ w_dec,        // (2,256)
                  const float* __restrict__ dpeproj,      // (2,1560)
                  const float* __restrict__ frame_noise,  // (256,120)
                  const float* __restrict__ joint_noise,  // (256,72,13)
                  float* __restrict__ out)                // (256,2,120,13)
{
    __shared__ __align__(16) char h_raw[NROW * 128];   // 64 KB bf16 [512][64]
    __shared__ float2 xm_sh[NROW];
    __shared__ int src_sh[NPOS];
    __shared__ short rev_sh[POS_PER_SAMPLE];           // -1 or position index
    __shared__ float pdpart[4][NPOS][2];               // per-ctg decoder partials
    __shared__ float noise_sh[T_FRAMES];
    __shared__ int rank_sh[T_FRAMES];
    __shared__ int ids_keep_sh[LEN_KEEP];
    __shared__ int tout_sh[LEN_KEEP];

    int n = blockIdx.x;
    int tid = threadIdx.x;
    int lane = tid & 63, wave = tid >> 6;
    int g = lane >> 4;       // k-group / D-row-group
    int r16 = lane & 15;     // A-row (channel) / B-col (position)
    int ctg = wave & 3;      // this wave's 4 channel-tiles: ct = ctg*4+i
    int ptg = wave >> 2;     // this wave's 16 position-tiles

    // ---- hoisted loads: w_enc A-fragments (8) + w_dec rows (8) per wave ----
    bf16x8 wfr[4][2];
    f32x4 wd0r[4], wd1r[4];
    {
        const bf16x8* wq = (const bf16x8*)wbf;
        #pragma unroll
        for (int i = 0; i < 4; ++i) {
            int ct = ctg * 4 + i;
            wfr[i][0] = wq[(ct * 16 + r16) * 8 + 0 + g];
            wfr[i][1] = wq[(ct * 16 + r16) * 8 + 4 + g];
            wd0r[i] = *(const f32x4*)(w_dec + ct * 16 + g * 4);
            wd1r[i] = *(const f32x4*)(w_dec + E_DIM + ct * 16 + g * 4);
        }
    }

    // ---- phase A: indices ----
    if (tid < T_FRAMES) noise_sh[tid] = frame_noise[n * T_FRAMES + tid];
    for (int i = tid; i < POS_PER_SAMPLE; i += THREADS) rev_sh[i] = -1;
    __syncthreads();

    if (tid < T_FRAMES) {
        float v = noise_sh[tid];
        int r = 0;
        for (int j = 0; j < T_FRAMES; ++j) {
            float u = noise_sh[j];
            r += (u < v || (u == v && j < tid)) ? 1 : 0;   // stable argsort rank
        }
        rank_sh[tid] = r;
    }
    __syncthreads();

    if (tid < T_FRAMES) {
        int kc = 0;                                  // #kept frames with index < tid
        for (int j = 0; j < tid; ++j) kc += (rank_sh[j] < LEN_KEEP) ? 1 : 0;
        if (rank_sh[tid] < LEN_KEEP) ids_keep_sh[kc] = tid;
        // tout_sh[v]: output frame t where frame_ids[t] == v (v < 72)
        if (tid < LEN_KEEP)
            tout_sh[tid] = (rank_sh[tid] < LEN_KEEP) ? kc : LEN_KEEP + (tid - kc);
    }
    __syncthreads();

    if (tid < LEN_KEEP) {
        int f = tid;
        const float* jn = joint_noise + (n * LEN_KEEP + f) * V_JOINTS;
        float jv[V_JOINTS];
        for (int v = 0; v < V_JOINTS; ++v) jv[v] = jn[v];
        int jrank[V_JOINTS];
        for (int v = 0; v < V_JOINTS; ++v) {
            int r = 0;
            for (int u = 0; u < V_JOINTS; ++u)
                r += (jv[u] < jv[v] || (jv[u] == jv[v] && u < v)) ? 1 : 0;
            jrank[v] = r;
        }
        int comb[V_JOINTS];
        int idx = 0;
        for (int v = 0; v < V_JOINTS; ++v) if (jrank[v] >= N_MASK_J) comb[idx++] = v;
        for (int v = 0; v < V_JOINTS; ++v) if (jrank[v] <  N_MASK_J) comb[idx++] = v;
        int vout[N_KEEP_J];
        for (int v = 0; v < V_JOINTS; ++v) {
            int s = comb[v];
            if (s < N_KEEP_J) vout[s] = v;
        }
        int tsrc = ids_keep_sh[f];
        int tout = tout_sh[f];
        for (int s = 0; s < N_KEEP_J; ++s) {
            int p = f * N_KEEP_J + s;
            src_sh[p] = tsrc * V_JOINTS + comb[s];
            int d = tout * V_JOINTS + vout[s];
            rev_sh[d] = (short)p;
        }
    }
    __syncthreads();

    // ---- phase B: gather x + pos_embed ----
    if (tid < NROW) {
        if (tid < NPOS) {
            int so = src_sh[tid];
            float x0 = x[(n * 2 + 0) * POS_PER_SAMPLE + so] + pos_embed[so];
            float x1 = x[(n * 2 + 1) * POS_PER_SAMPLE + so] + pos_embed[POS_PER_SAMPLE + so];
            xm_sh[tid] = make_float2(x0, x1);
        } else {
            xm_sh[tid] = make_float2(0.f, 0.f);
        }
    }
    __syncthreads();

    // ---- phase C: h[p][k] = leaky(w_in[k,:].xm[p] + b[k]) -> bf16 LDS ----
    {
        int kq = lane;
        float wi0 = w_in[kq * 2 + 0], wi1 = w_in[kq * 2 + 1], bk = b_in[kq];
        for (int p = wave; p < NROW; p += 8) {
            float2 xm = xm_sh[p];
            float hv = fmaf(wi0, xm.x, fmaf(wi1, xm.y, bk));
            hv = fmaxf(hv, 0.1f * hv);                    // leaky
            int off = (p * 128 + kq * 2) ^ ((p & 7) << 4);
            *(__bf16*)(h_raw + off) = (__bf16)hv;
        }
    }
    __syncthreads();

    // ---- phase D: MFMA e-stage + fused decoder ----
    // wave (ctg,ptg): channels [ctg*64, ctg*64+64), tiles [ptg*16, ptg*16+16)
    for (int t = 0; t < 16; ++t) {
        int pt = ptg * 16 + t;
        int row = pt * 16 + r16;
        int swz = (row & 7) << 4;
        bf16x8 b0 = *(const bf16x8*)(h_raw + ((row * 128 + g * 16) ^ swz));
        bf16x8 b1 = *(const bf16x8*)(h_raw + ((row * 128 + 64 + g * 16) ^ swz));

        float pd0 = 0.f, pd1 = 0.f;
        #pragma unroll
        for (int i = 0; i < 4; ++i) {
            f32x4 acc = {0.f, 0.f, 0.f, 0.f};
            acc = __builtin_amdgcn_mfma_f32_16x16x32_bf16(wfr[i][0], b0, acc, 0, 0, 0);
            acc = __builtin_amdgcn_mfma_f32_16x16x32_bf16(wfr[i][1], b1, acc, 0, 0, 0);
            // D layout: channel c = (ctg*4+i)*16 + g*4 + r, position p = pt*16 + r16
            #pragma unroll
            for (int r = 0; r < 4; ++r) {
                float e = acc[r];
                e = fmaxf(e, 0.1f * e);                   // leaky
                pd0 = fmaf(wd0r[i][r], e, pd0);
                pd1 = fmaf(wd1r[i][r], e, pd1);
            }
        }
        // reduce over the 4 g-groups (lane bits 4,5)
        pd0 += __shfl_xor(pd0, 16); pd0 += __shfl_xor(pd0, 32);
        pd1 += __shfl_xor(pd1, 16); pd1 += __shfl_xor(pd1, 32);

        int p = pt * 16 + r16;
        if (lane < 16 && p < NPOS) {
            pdpart[ctg][p][0] = pd0;
            pdpart[ctg][p][1] = pd1;
        }
    }
    __syncthreads();

    // ---- phase E: final write: out = dpeproj + scattered decoder result ----
    {
        float* outn = out + n * C_IN * POS_PER_SAMPLE;
        for (int i = tid; i < C_IN * POS_PER_SAMPLE; i += THREADS) {
            int o = (i >= POS_PER_SAMPLE) ? 1 : 0;
            int pos = i - o * POS_PER_SAMPLE;
            float v = dpeproj[i];
            int p = rev_sh[pos];
            if (p >= 0)
                v += pdpart[0][p][o] + pdpart[1][p][o]
                   + pdpart[2][p][o] + pdpart[3][p][o];
            outn[i] = v;
        }
    }
}

// ---------------------------------------------------------------------------
extern "C" void kernel_launch(void* const* d_in, const int* in_sizes, int n_in,
                              void* d_out, int out_size, void* d_ws, size_t ws_size,
                              hipStream_t stream) {
    const float* x             = (const float*)d_in[0];
    const float* frame_noise   = (const float*)d_in[1];
    const float* joint_noise   = (const float*)d_in[2];
    const float* pos_embed     = (const float*)d_in[3];
    const float* dec_pos_embed = (const float*)d_in[4];
    const float* w_in          = (const float*)d_in[5];
    const float* b_in          = (const float*)d_in[6];
    const float* w_enc         = (const float*)d_in[7];
    const float* w_dec         = (const float*)d_in[8];
    float* out = (float*)d_out;

    // ws layout: dpeproj (3120 f32, 12480 B, 16B-aligned) then wbf (16384 bf16)
    float* dpeproj = (float*)d_ws;
    __bf16* wbf    = (__bf16*)(dpeproj + C_IN * POS_PER_SAMPLE);

    prep_kernel<<<77, 256, 0, stream>>>(w_dec, dec_pos_embed, w_enc, dpeproj, wbf);

    fused_kernel<<<N_SAMP, THREADS, 0, stream>>>(
        x, pos_embed, w_in, b_in, wbf, w_dec, dpeproj,
        frame_noise, joint_noise, out);
}